// Round 8
// baseline (533.484 us; speedup 1.0000x reference)
//
#include <hip/hip_runtime.h>
#include <stdint.h>
#include <math.h>

#define BB 4
#define NN 8192
#define DD 1024
#define HH 16
#define DHH 64
#define NQc 1024
#define NKVc 2048
#define EPS_ 0.1f
#define NITERS 20

typedef unsigned long long u64;
typedef __attribute__((ext_vector_type(8))) short bfrag8;   // 8 bf16 = 4 VGPRs (MFMA A/B)
typedef __attribute__((ext_vector_type(4))) float f32x4;    // MFMA C/D
typedef __attribute__((ext_vector_type(4))) short short4v;

#define MFMA_BF16(a, b, c) __builtin_amdgcn_mfma_f32_16x16x32_bf16(a, b, c, 0, 0, 0)

// async global->LDS, 16B per lane; LDS dest = wave-uniform base + lane*16
#define GLOAD16(gp, lp) __builtin_amdgcn_global_load_lds( \
    (const __attribute__((address_space(1))) void*)(gp),  \
    (__attribute__((address_space(3))) void*)(lp), 16, 0, 0)

static __device__ inline short f2bf(float f) {
  uint32_t u = __float_as_uint(f);
  uint32_t r = (u + 0x7fffu + ((u >> 16) & 1u)) >> 16;   // round-to-nearest-even
  return (short)r;
}
static __device__ inline short f2bf_fast(float f) {       // round-half-up (2 inst)
  return (short)((__float_as_uint(f) + 0x8000u) >> 16);
}
static __device__ inline float bf2f(short s) {
  return __uint_as_float(((uint32_t)(uint16_t)s) << 16);
}

// ---------------- router logits: PURE-READ stream, weights in registers ----------------
// 2048 blocks x 256 threads = 8192 waves; each wave does 4 rows (stride 8192).
// Bit-identical dot order to the old fused kernel (c-loop, float4 lanes, same reduce).
__global__ __launch_bounds__(256) void k_logits(
    const float* __restrict__ x, const float* __restrict__ wq,
    const float* __restrict__ wkv,
    float* __restrict__ logq, float* __restrict__ logkv)
{
  int tid = threadIdx.x;
  int lane = tid & 63;
  float4 wq4[4], wkv4[4];
#pragma unroll
  for (int c = 0; c < 4; c++) {
    wq4[c]  = ((const float4*)wq)[c * 64 + lane];
    wkv4[c] = ((const float4*)wkv)[c * 64 + lane];
  }
  int gw = (blockIdx.x * 256 + tid) >> 6;   // 0..8191
  for (int row = gw; row < BB * NN; row += 8192) {
    const float4* xr = (const float4*)(x + (size_t)row * DD);
    float dq = 0.f, dkv = 0.f;
#pragma unroll
    for (int c = 0; c < 4; c++) {
      float4 xv = xr[c * 64 + lane];
      dq  += xv.x*wq4[c].x  + xv.y*wq4[c].y  + xv.z*wq4[c].z  + xv.w*wq4[c].w;
      dkv += xv.x*wkv4[c].x + xv.y*wkv4[c].y + xv.z*wkv4[c].z + xv.w*wkv4[c].w;
    }
#pragma unroll
    for (int off = 32; off > 0; off >>= 1) {
      dq  += __shfl_xor(dq, off);
      dkv += __shfl_xor(dkv, off);
    }
    if (lane == 0) { logq[row] = dq; logkv[row] = dkv; }
  }
}

// ---------------- null-token base fill: PURE-WRITE stream ----------------
// 2048 blocks x 256 threads; stride (524288 float4s) is a multiple of 256, so
// each thread's column slot (tid&255) is invariant -> one register, pure writes.
__global__ __launch_bounds__(256) void k_fill(
    const float* __restrict__ nulltok, float* __restrict__ out)
{
  int t = blockIdx.x * 256 + threadIdx.x;       // 0..524287
  float4 v = ((const float4*)nulltok)[t & 255];
  float4* o = (float4*)out;
  const size_t total = (size_t)BB * NN * DD / 4;   // 8,388,608 float4s
  for (size_t i = t; i < total; i += 524288)
    o[i] = v;
}

// ---------------- Kernel B: coor-descent + exact top-k via radix select ----------------
// blocks 0..3: q-router (k=NQ), blocks 4..7: kv-router (k=NKV)
__global__ __launch_bounds__(1024) void k_route2(
    const float* __restrict__ logq_g, const float* __restrict__ logkv_g,
    float cq, float ckv,
    int* __restrict__ qtok, int* __restrict__ qmap,
    int* __restrict__ kvtok, int* __restrict__ kvmap)
{
  __shared__ float redf[2][16];
  __shared__ unsigned int hist[256];
  __shared__ int wsum[16];
  __shared__ int scal[2];
  int sel = blockIdx.x >> 2, b = blockIdx.x & 3;
  const float* logits = sel ? logkv_g : logq_g;
  int k = sel ? NKVc : NQc;
  float constant = sel ? ckv : cq;
  int* tok = sel ? kvtok : qtok;
  int* map = sel ? kvmap : qmap;
  int tid = threadIdx.x;
  int lane = tid & 63, wv = tid >> 6;
  const float4* lg = (const float4*)(logits + (size_t)b * NN);
  float s[8];
  float4 v0 = lg[tid * 2], v1 = lg[tid * 2 + 1];
  s[0]=v0.x; s[1]=v0.y; s[2]=v0.z; s[3]=v0.w;
  s[4]=v1.x; s[5]=v1.y; s[6]=v1.z; s[7]=v1.w;

  // one-time block max of s
  float m = s[0];
#pragma unroll
  for (int e = 1; e < 8; e++) m = fmaxf(m, s[e]);
#pragma unroll
  for (int off = 32; off > 0; off >>= 1) m = fmaxf(m, __shfl_xor(m, off));
  if (lane == 0) redf[0][wv] = m;
  __syncthreads();
  float maxs = redf[0][0];
  for (int i = 1; i < 16; i++) maxs = fmaxf(maxs, redf[0][i]);

  // iteration 1 closed-form: b = -s -> t = 0 -> lse = log(NN) exactly
  float a = constant - EPS_ * logf((float)NN);
  for (int it = 1; it < NITERS; it++) {
    float na = -a;
    float mm = fminf(maxs, na);
    float sum = 0.f;
#pragma unroll
    for (int e = 0; e < 8; e++) sum += expf((fminf(s[e], na) - mm) * (1.f / EPS_));
#pragma unroll
    for (int off = 32; off > 0; off >>= 1) sum += __shfl_xor(sum, off);
    if (lane == 0) redf[it & 1][wv] = sum;
    __syncthreads();
    float ss = redf[it & 1][0];
    for (int i = 1; i < 16; i++) ss += redf[it & 1][i];
    a = constant - mm - EPS_ * logf(ss);
  }

  // packed 43-bit keys: score float bits (<=0x3F800000, 30 bits) << 13 | (NN-1-i)
  u64 key[8];
#pragma unroll
  for (int e = 0; e < 8; e++) {
    int i = tid * 8 + e;
    float sc = expf(fminf(s[e] + a, 0.f) * (1.f / EPS_));
    key[e] = ((u64)__float_as_uint(sc) << 13) | (u64)(NN - 1 - i);
  }

  // 6-pass MSD radix select for the exact k-th largest key (keys all distinct)
  int kp = k;
  u64 pref = 0;
  for (int d = 5; d >= 0; d--) {
    int sh = d * 8;
    if (tid < 256) hist[tid] = 0;
    __syncthreads();
#pragma unroll
    for (int e = 0; e < 8; e++) {
      if ((key[e] >> (sh + 8)) == pref)
        atomicAdd(&hist[(unsigned)(key[e] >> sh) & 255u], 1u);
    }
    __syncthreads();
    if (wv == 0) {
      unsigned cc[4];
#pragma unroll
      for (int t = 0; t < 4; t++) cc[t] = hist[lane * 4 + t];
      unsigned g = cc[0] + cc[1] + cc[2] + cc[3];
      unsigned sfx = g;                       // inclusive suffix sum across lanes
#pragma unroll
      for (int off = 1; off < 64; off <<= 1) {
        unsigned t = __shfl_down(sfx, off);
        if (lane + off < 64) sfx += t;
      }
      unsigned aft0 = __shfl_down(sfx, 1);
      unsigned after = (lane == 63) ? 0u : aft0;   // count in lanes > this one
      if (sfx >= (unsigned)kp && after < (unsigned)kp) {
        unsigned above = after;
        int bin = 3;
        if (above + cc[3] < (unsigned)kp) { above += cc[3]; bin = 2;
          if (above + cc[2] < (unsigned)kp) { above += cc[2]; bin = 1;
            if (above + cc[1] < (unsigned)kp) { above += cc[1]; bin = 0; } } }
        scal[0] = lane * 4 + bin;
        scal[1] = kp - (int)above;
      }
    }
    __syncthreads();
    pref = (pref << 8) | (unsigned)scal[0];
    kp = scal[1];
  }
  u64 kth = pref;   // exact key of the k-th largest; count(key >= kth) == k

  // stream-compact selected indices (index-ascending order)
  int flag[8], cnt = 0;
#pragma unroll
  for (int e = 0; e < 8; e++) { flag[e] = (key[e] >= kth) ? 1 : 0; cnt += flag[e]; }
  int incl = cnt;
#pragma unroll
  for (int off = 1; off < 64; off <<= 1) {
    int t3 = __shfl_up(incl, off);
    if (lane >= off) incl += t3;
  }
  if (lane == 63) wsum[wv] = incl;
  __syncthreads();
  int wbase = 0;
  for (int w2 = 0; w2 < wv; w2++) wbase += wsum[w2];
  int pos = wbase + incl - cnt;
  int bbase = b * k;
#pragma unroll
  for (int e = 0; e < 8; e++) {
    if (flag[e]) {
      int i = tid * 8 + e;
      tok[bbase + pos] = i;
      map[bbase + pos] = b * NN + i;
      pos++;
    }
  }
}

// ---------------- gather routed rows of x -> compact bf16 A matrix ----------------
// Single launch covers BOTH routers: map = qmap (kvmap contiguous after),
// A = Aq (Akv contiguous after). 3072 blocks = 12288 rows.
__global__ __launch_bounds__(256) void k_gather(
    const float* __restrict__ x, const int* __restrict__ map, short* __restrict__ A)
{
  int row = blockIdx.x * 4 + (threadIdx.x >> 6);
  int lane = threadIdx.x & 63;
  int src = map[row];
  const float4* xr = (const float4*)(x + (size_t)src * DD);
  short4v* ar = (short4v*)(A + (size_t)row * DD);
#pragma unroll
  for (int c = 0; c < 4; c++) {
    float4 v = xr[c * 64 + lane];
    short4v s;
    s[0] = f2bf(v.x); s[1] = f2bf(v.y); s[2] = f2bf(v.z); s[3] = f2bf(v.w);
    ar[c * 64 + lane] = s;
  }
}

// ---------------- all 3 weight transposes in ONE launch ----------------
// blocks 0..255: wq(16x16), 256..767: wkv(32x16), 768..1023: wout(16x16)
__global__ __launch_bounds__(256) void k_wt_all(
    const float* __restrict__ wq, const float* __restrict__ wkv,
    const float* __restrict__ wout,
    short* __restrict__ wqT, short* __restrict__ wkvT, short* __restrict__ woutT)
{
  __shared__ float t[64][65];
  int bid = blockIdx.x;
  const float* W; short* WT; int N, bx, by;
  if (bid < 256)      { W = wq;   WT = wqT;   N = 1024; bx = bid & 15;         by = bid >> 4; }
  else if (bid < 768) { W = wkv;  WT = wkvT;  N = 2048; bx = (bid - 256) & 31; by = (bid - 256) >> 5; }
  else                { W = wout; WT = woutT; N = 1024; bx = (bid - 768) & 15; by = (bid - 768) >> 4; }
  const int K = 1024;
  int n0 = bx * 64, k0 = by * 64;
  int c = threadIdx.x & 63, r0 = (threadIdx.x >> 6) * 16;
#pragma unroll
  for (int rr = 0; rr < 16; rr++)
    t[r0 + rr][c] = W[(size_t)(k0 + r0 + rr) * N + n0 + c];
  __syncthreads();
#pragma unroll
  for (int rr = 0; rr < 16; rr++)
    WT[(size_t)(n0 + r0 + rr) * K + k0 + c] = f2bf(t[c][r0 + rr]);
}

// ---------------- bf16 MFMA GEMM: C = A[M][K] @ BT[N][K]^T ----------------
// 128x128 tile, BK=32, 4 waves (2x2) of 64x64.
// DOUBLE-BUFFERED global_load_lds pipeline: ONE barrier per K-step (round-3
// measured-good version — no source swizzle, no fused rotary).
// XCD-aware block swizzle. mode 2: K half -> khb [bh][t][d]; V half -> vhbT
// [bh][d][t] (transposed).
__global__ __launch_bounds__(256) void k_gemm_mfma(
    const short* __restrict__ A, const short* __restrict__ BT, int Kdim,
    float* __restrict__ Cf, short* __restrict__ Cb0, short* __restrict__ Cb1,
    const int* __restrict__ rowmapC, int mode)
{
  #define PBUF (128 * 32)   // shorts per LDS buffer
  __shared__ short As[2 * PBUF];
  __shared__ short Bs[2 * PBUF];
  int tid = threadIdx.x;
  int lane = tid & 63, wv = tid >> 6;

  // XCD swizzle: contiguous chunk of tile space per XCD (nwg % 8 == 0 here)
  int nwg = gridDim.x * gridDim.y;
  int bid = blockIdx.y * gridDim.x + blockIdx.x;
  int cpx = nwg >> 3;
  int swz = (bid & 7) * cpx + (bid >> 3);
  int m0 = (swz / gridDim.x) * 128, n0 = (swz % gridDim.x) * 128;

  int wm = (wv >> 1) * 64, wn = (wv & 1) * 64;
  int fr = lane & 15, quad = lane >> 4;

  int c0 = wv * 128 + lane;
  int c1 = c0 + 64;
  const short* gA0 = A  + (size_t)(m0 + (c0 >> 2)) * Kdim + (c0 & 3) * 8;
  const short* gA1 = A  + (size_t)(m0 + (c1 >> 2)) * Kdim + (c1 & 3) * 8;
  const short* gB0 = BT + (size_t)(n0 + (c0 >> 2)) * Kdim + (c0 & 3) * 8;
  const short* gB1 = BT + (size_t)(n0 + (c1 >> 2)) * Kdim + (c1 & 3) * 8;
  short* lA0 = As + wv * 1024;
  short* lA1 = As + wv * 1024 + 512;
  short* lB0 = Bs + wv * 1024;
  short* lB1 = Bs + wv * 1024 + 512;

  f32x4 acc[4][4];
#pragma unroll
  for (int i = 0; i < 4; i++)
#pragma unroll
    for (int j = 0; j < 4; j++) {
      acc[i][j][0] = 0.f; acc[i][j][1] = 0.f; acc[i][j][2] = 0.f; acc[i][j][3] = 0.f;
    }

  // prologue: stage K-step 0 into buffer 0, drain, join
  GLOAD16(gA0, lA0);
  GLOAD16(gA1, lA1);
  GLOAD16(gB0, lB0);
  GLOAD16(gB1, lB1);
  __syncthreads();

  for (int k0 = 0; k0 < Kdim; k0 += 32) {
    int cur = (k0 >> 5) & 1, nxt = cur ^ 1;
    if (k0 + 32 < Kdim) {   // issue next K-step's loads; they fly during compute
      GLOAD16(gA0 + k0 + 32, lA0 + nxt * PBUF);
      GLOAD16(gA1 + k0 + 32, lA1 + nxt * PBUF);
      GLOAD16(gB0 + k0 + 32, lB0 + nxt * PBUF);
      GLOAD16(gB1 + k0 + 32, lB1 + nxt * PBUF);
    }
    const short* Ab = As + cur * PBUF;
    const short* Bb = Bs + cur * PBUF;
    bfrag8 af[4], bf[4];
#pragma unroll
    for (int t = 0; t < 4; t++) {
      af[t] = *(const bfrag8*)&Ab[(wm + t * 16 + fr) * 32 + quad * 8];
      bf[t] = *(const bfrag8*)&Bb[(wn + t * 16 + fr) * 32 + quad * 8];
    }
#pragma unroll
    for (int mt = 0; mt < 4; mt++)
#pragma unroll
      for (int nt = 0; nt < 4; nt++)
        acc[mt][nt] = MFMA_BF16(af[mt], bf[nt], acc[mt][nt]);
    __syncthreads();   // drains vmcnt: next buffer ready; also protects reuse
  }

#pragma unroll
  for (int mt = 0; mt < 4; mt++) {
#pragma unroll
    for (int nt = 0; nt < 4; nt++) {
#pragma unroll
      for (int r = 0; r < 4; r++) {
        int grow = m0 + wm + mt * 16 + quad * 4 + r;
        int gcol = n0 + wn + nt * 16 + fr;
        float v = acc[mt][nt][r];
        if (mode == 0) {
          int gr = rowmapC[grow];
          Cf[(size_t)gr * 1024 + gcol] = v;
        } else if (mode == 1) {
          int b = grow >> 10, q = grow & 1023;
          int h = gcol >> 6, d = gcol & 63;
          Cb0[((size_t)(b * HH + h) * NQc + q) * DHH + d] = f2bf(v);
        } else {
          int b = grow >> 11, t = grow & 2047;
          if (gcol < 1024) {
            int h = gcol >> 6, d = gcol & 63;
            Cb0[((size_t)(b * HH + h) * NKVc + t) * DHH + d] = f2bf(v);
          } else {
            int c2 = gcol - 1024, h = c2 >> 6, d = c2 & 63;
            Cb1[((size_t)(b * HH + h) * DHH + d) * NKVc + t] = f2bf(v);
          }
        }
      }
    }
  }
  #undef PBUF
}

// ---------------- rotary, in-place on bf16 ----------------
// qhb gets SCALE=0.125 folded in.
__global__ __launch_bounds__(256) void k_rot_q(
    short* __restrict__ qhb, const float* __restrict__ rotary, const int* __restrict__ qtok)
{
  int gw = (blockIdx.x * 256 + threadIdx.x) >> 6;
  int lane = threadIdx.x & 63;
  int b = gw >> 14, rem = gw & 16383, h = rem >> 10, q = rem & 1023;
  int tokid = qtok[b * NQc + q];
  float p = rotary[(size_t)tokid * DHH + lane];
  size_t base = ((size_t)(b * HH + h) * NQc + q) * DHH;
  float t = bf2f(qhb[base + lane]);
  float partner = __shfl_xor(t, 32);
  float rh = (lane < 32) ? -partner : partner;
  qhb[base + lane] = f2bf((t * cosf(p) + rh * sinf(p)) * 0.125f);
}

// K rotary only (null k/v handled in-register inside attention).
__global__ __launch_bounds__(256) void k_rot_k(
    short* __restrict__ khb, const float* __restrict__ rotary,
    const int* __restrict__ kvtok)
{
  int gw = (blockIdx.x * 256 + threadIdx.x) >> 6;   // 0..131071
  int lane = threadIdx.x & 63;
  int b = gw >> 15, rem = gw & 32767, h = rem >> 11, j = rem & 2047;
  int tokid = kvtok[b * NKVc + j];
  float p = rotary[(size_t)tokid * DHH + lane];
  size_t base = ((size_t)(b * HH + h) * NKVc + j) * DHH;
  float t = bf2f(khb[base + lane]);
  float partner = __shfl_xor(t, 32);
  float rh = (lane < 32) ? -partner : partner;
  khb[base + lane] = f2bf(t * cosf(p) + rh * sinf(p));
}

// ---------------- MFMA flash attention (bf16 in, bf16 out) ----------------
// Grid 512 flat, XCD-swizzled. Block = 4 waves x 32 q-rows. 64-key LDS tiles.
// 32 clean tiles; null k/v handled in-register outside the loop. Register-
// prefetch double-buffered staging, ONE raw s_barrier per tile. Static softmax.
#define KP 72    // K/V row pitch (shorts): 144 B -> 2-way frag reads (free)
#define PP2 72   // P row pitch (shorts)
__global__ __launch_bounds__(256) void k_attn_mfma(
    const short* __restrict__ qhb, const short* __restrict__ khb,
    const short* __restrict__ vhbT, const float* __restrict__ nullkv,
    short* __restrict__ attnb)
{
  __shared__ short Kt[2][64][KP];    // [buf][key][d]
  __shared__ short Vt[2][64][KP];    // [buf][d][key]
  __shared__ short Pb[4][16][PP2];   // per-wave P: [q(16)][key(64)]
  int tid = threadIdx.x;
  int lane = tid & 63, wv = tid >> 6;
  int bid = blockIdx.x;
  int xcd = bid & 7, j = bid >> 3;
  int bh = xcd * 8 + (j & 7);
  int qb = j >> 3;
  int q0 = qb * 128 + wv * 32;
  int fr = lane & 15, quad = lane >> 4;
  int b = bh >> 4, h = bh & 15;

  bfrag8 onesf;
#pragma unroll
  for (int e = 0; e < 8; e++) onesf[e] = (short)0x3F80;   // bf16 1.0

  bfrag8 qf[2][2];
#pragma unroll
  for (int qg = 0; qg < 2; qg++) {
    const short* qbase = qhb + ((size_t)bh * NQc + q0 + qg * 16 + fr) * DHH + quad * 8;
    qf[qg][0] = *(const bfrag8*)(qbase);
    qf[qg][1] = *(const bfrag8*)(qbase + 32);
  }

  // ---- null-key score s_null = q_row . k_null (q already rotary+scaled) ----
  float sn[2];
#pragma unroll
  for (int qg = 0; qg < 2; qg++) {
    float accn = 0.f;
#pragma unroll
    for (int e = 0; e < 8; e++) {
      accn += bf2f(qf[qg][0][e]) * nullkv[h * DHH + quad * 8 + e];
      accn += bf2f(qf[qg][1][e]) * nullkv[h * DHH + 32 + quad * 8 + e];
    }
    accn += __shfl_xor(accn, 16);
    accn += __shfl_xor(accn, 32);
    sn[qg] = accn;
  }
  float vn[4];
#pragma unroll
  for (int g = 0; g < 4; g++) vn[g] = nullkv[(HH + h) * DHH + g * 16 + fr];

  f32x4 o[2][4], l4[2];
#pragma unroll
  for (int qg = 0; qg < 2; qg++) {
#pragma unroll
    for (int g = 0; g < 4; g++) {
      o[qg][g][0]=0.f; o[qg][g][1]=0.f; o[qg][g][2]=0.f; o[qg][g][3]=0.f;
    }
    l4[qg][0]=0.f; l4[qg][1]=0.f; l4[qg][2]=0.f; l4[qg][3]=0.f;
  }

  int rr = tid >> 3, ch8 = (tid & 7) * 8;
  const short* kp0 = khb + (size_t)bh * NKVc * DHH + (size_t)rr * DHH + ch8;
  const short* kp1 = kp0 + 32 * DHH;
  const short* vp0 = vhbT + ((size_t)bh * DHH + rr) * NKVc + ch8;
  const short* vp1 = vp0 + (size_t)32 * NKVc;

  bfrag8 kr0 = *(const bfrag8*)kp0;
  bfrag8 kr1 = *(const bfrag8*)kp1;
  bfrag8 vr0 = *(const bfrag8*)vp0;
  bfrag8 vr1 = *(const bfrag8*)vp1;

  for (int t = 0; t < 32; t++) {
    int cur = t & 1;
    *(bfrag8*)&Kt[cur][rr][ch8]      = kr0;
    *(bfrag8*)&Kt[cur][rr + 32][ch8] = kr1;
    *(bfrag8*)&Vt[cur][rr][ch8]      = vr0;
    *(bfrag8*)&Vt[cur][rr + 32][ch8] = vr1;
    if (t < 31) {
      size_t ko = (size_t)(t + 1) * 64 * DHH;
      size_t vo = (size_t)(t + 1) * 64;
      kr0 = *(const bfrag8*)(kp0 + ko);
      kr1 = *(const bfrag8*)(kp1 + ko);
      vr0 = *(const bfrag8*)(vp0 + vo);
      vr1 = *(const bfrag8*)(vp1 + vo);
    }
    __builtin_amdgcn_sched_barrier(0);
    asm volatile("s_waitcnt lgkmcnt(0)" ::: "memory");
    __builtin_amdgcn_s_barrier();
    __builtin_amdgcn_sched_barrier(0);

    bfrag8 kf[4][2], vf[4][2];
#pragma unroll
    for (int g = 0; g < 4; g++) {
      kf[g][0] = *(const bfrag8*)&Kt[cur][g * 16 + fr][quad * 8];
      kf[g][1] = *(const bfrag8*)&Kt[cur][g * 16 + fr][32 + quad * 8];
      vf[g][0] = *(const bfrag8*)&Vt[cur][g * 16 + fr][quad * 8];
      vf[g][1] = *(const bfrag8*)&Vt[cur][g * 16 + fr][32 + quad * 8];
    }

#pragma unroll
    for (int qg = 0; qg < 2; qg++) {
      f32x4 sa[4];
#pragma unroll
      for (int g = 0; g < 4; g++) { sa[g][0]=0.f; sa[g][1]=0.f; sa[g][2]=0.f; sa[g][3]=0.f; }
#pragma unroll
      for (int g = 0; g < 4; g++) {
        sa[g] = MFMA_BF16(kf[g][0], qf[qg][0], sa[g]);
        sa[g] = MFMA_BF16(kf[g][1], qf[qg][1], sa[g]);
      }
#pragma unroll
      for (int g = 0; g < 4; g++) {
        short4v p4;
#pragma unroll
        for (int r = 0; r < 4; r++) p4[r] = f2bf_fast(__expf(sa[g][r]));
        *(short4v*)&Pb[wv][fr][g * 16 + quad * 4] = p4;
      }
      bfrag8 pf0 = *(const bfrag8*)&Pb[wv][fr][quad * 8];
      bfrag8 pf1 = *(const bfrag8*)&Pb[wv][fr][32 + quad * 8];
      l4[qg] = MFMA_BF16(pf0, onesf, l4[qg]);
      l4[qg] = MFMA_BF16(pf1, onesf, l4[qg]);
#pragma unroll
      for (int g = 0; g < 4; g++) {
        o[qg][g] = MFMA_BF16(pf0, vf[g][0], o[qg][g]);
        o[qg][g] = MFMA_BF16(pf1, vf[g][1], o[qg][g]);
      }
    }
  }

#pragma unroll
  for (int qg = 0; qg < 2; qg++) {
    float pn[4];
#pragma unroll
    for (int r = 0; r < 4; r++) {
      pn[r] = __expf(__shfl(sn[qg], quad * 4 + r));
      l4[qg][r] += pn[r];
    }
#pragma unroll
    for (int g = 0; g < 4; g++)
#pragma unroll
      for (int r = 0; r < 4; r++)
        o[qg][g][r] += pn[r] * vn[g];
  }
#pragma unroll
  for (int qg = 0; qg < 2; qg++) {
    float inv[4];
#pragma unroll
    for (int r = 0; r < 4; r++) inv[r] = 1.f / l4[qg][r];
#pragma unroll
    for (int r = 0; r < 4; r++) {
      size_t row = (size_t)(b * NQc + q0 + qg * 16 + quad * 4 + r) * DD + h * DHH;
#pragma unroll
      for (int g = 0; g < 4; g++)
        attnb[row + g * 16 + fr] = f2bf(o[qg][g][r] * inv[r]);
    }
  }
}

extern "C" void kernel_launch(void* const* d_in, const int* in_sizes, int n_in,
                              void* d_out, int out_size, void* d_ws, size_t ws_size,
                              hipStream_t stream)
{
  const float* x       = (const float*)d_in[0];
  const float* rotary  = (const float*)d_in[1];
  const float* wrq     = (const float*)d_in[2];
  const float* wrkv    = (const float*)d_in[3];
  const float* wq      = (const float*)d_in[4];
  const float* wkv     = (const float*)d_in[5];
  const float* wout    = (const float*)d_in[6];
  const float* nullkv  = (const float*)d_in[7];
  const float* nulltok = (const float*)d_in[8];
  float* out = (float*)d_out;
  float* ws  = (float*)d_ws;

  // workspace (float offsets), total 21,061,632 floats ~ 84.25 MB (round-3 proven)
  float* logq  = ws;                  // 32768
  float* logkv = ws + 32768;          // 32768
  int*   qtok  = (int*)(ws + 65536);  // 4096
  int*   kvtok = (int*)(ws + 69632);  // 8192
  int*   qmap  = (int*)(ws + 77824);  // 4096 (kvmap contiguous after — k_gather relies on it)
  int*   kvmap = (int*)(ws + 81920);  // 8192 -> 90112
  short* qhb   = (short*)(ws + 90112);     // 4,194,304 sh -> 2,187,264
  short* khb   = (short*)(ws + 2187264);   // 8,388,608 sh -> 6,381,568
  short* vhbT  = (short*)(ws + 6381568);   // 8,388,608 sh -> 10,575,872
  short* attnb = (short*)(ws + 10575872);  // 4,194,304 sh -> 12,673,024
  short* Aq    = (short*)(ws + 12673024);  // 4096*1024 sh (Akv contiguous after)
  short* wqT   = (short*)(ws + 18964480);  // 1024*1024 sh -> 19,488,768
  short* wkvT  = (short*)(ws + 19488768);  // 2048*1024 sh -> 20,537,344
  short* woutT = (short*)(ws + 20537344);  // 1024*1024 sh -> 21,061,632
  short* Akv   = Aq + (size_t)4096 * 1024;

  k_logits<<<2048, 256, 0, stream>>>(x, wrq, wrkv, logq, logkv);
  k_route2<<<8, 1024, 0, stream>>>(logq, logkv, 0.1f * logf(1152.f), 0.1f * logf(2304.f),
                                   qtok, qmap, kvtok, kvmap);
  k_wt_all<<<1024, 256, 0, stream>>>(wq, wkv, wout, wqT, wkvT, woutT);
  k_gather<<<3072, 256, 0, stream>>>(x, qmap, Aq);   // covers Aq AND Akv
  // q proj: M=4096 N=1024
  k_gemm_mfma<<<dim3(8, 32), 256, 0, stream>>>(Aq, wqT, 1024, nullptr, qhb, nullptr,
                                               nullptr, 1);
  // kv proj: M=8192 N=2048 (K half -> khb rows, V half -> vhbT transposed)
  k_gemm_mfma<<<dim3(16, 64), 256, 0, stream>>>(Akv, wkvT, 1024, nullptr, khb, vhbT,
                                                nullptr, 2);
  k_rot_q<<<16384, 256, 0, stream>>>(qhb, rotary, qtok);
  k_rot_k<<<32768, 256, 0, stream>>>(khb, rotary, kvtok);
  k_attn_mfma<<<512, 256, 0, stream>>>(qhb, khb, vhbT, nullkv, attnb);
  // null-token base fill (pure-write stream), must precede the scatter below
  k_fill<<<2048, 256, 0, stream>>>(nulltok, out);
  // out proj: M=4096 N=1024, scatter rows via qmap
  k_gemm_mfma<<<dim3(8, 32), 256, 0, stream>>>(attnb, woutT, 1024, out, nullptr, nullptr,
                                               qmap, 0);
}

// Round 9
// 475.735 us; speedup vs baseline: 1.1214x; 1.1214x over previous
//
#include <hip/hip_runtime.h>
#include <stdint.h>
#include <math.h>

#define BB 4
#define NN 8192
#define DD 1024
#define HH 16
#define DHH 64
#define NQc 1024
#define NKVc 2048
#define EPS_ 0.1f
#define NITERS 20

typedef unsigned long long u64;
typedef __attribute__((ext_vector_type(8))) short bfrag8;   // 8 bf16 = 4 VGPRs (MFMA A/B)
typedef __attribute__((ext_vector_type(4))) float f32x4;    // MFMA C/D
typedef __attribute__((ext_vector_type(4))) short short4v;

#define MFMA_BF16(a, b, c) __builtin_amdgcn_mfma_f32_16x16x32_bf16(a, b, c, 0, 0, 0)

// async global->LDS, 16B per lane; LDS dest = wave-uniform base + lane*16
#define GLOAD16(gp, lp) __builtin_amdgcn_global_load_lds( \
    (const __attribute__((address_space(1))) void*)(gp),  \
    (__attribute__((address_space(3))) void*)(lp), 16, 0, 0)

static __device__ inline short f2bf(float f) {
  uint32_t u = __float_as_uint(f);
  uint32_t r = (u + 0x7fffu + ((u >> 16) & 1u)) >> 16;   // round-to-nearest-even
  return (short)r;
}
static __device__ inline short f2bf_fast(float f) {       // round-half-up (2 inst)
  return (short)((__float_as_uint(f) + 0x8000u) >> 16);
}
static __device__ inline float bf2f(short s) {
  return __uint_as_float(((uint32_t)(uint16_t)s) << 16);
}

// ---------------- router logits: PURE-READ stream, weights in registers ----------------
__global__ __launch_bounds__(256) void k_logits(
    const float* __restrict__ x, const float* __restrict__ wq,
    const float* __restrict__ wkv,
    float* __restrict__ logq, float* __restrict__ logkv)
{
  int tid = threadIdx.x;
  int lane = tid & 63;
  float4 wq4[4], wkv4[4];
#pragma unroll
  for (int c = 0; c < 4; c++) {
    wq4[c]  = ((const float4*)wq)[c * 64 + lane];
    wkv4[c] = ((const float4*)wkv)[c * 64 + lane];
  }
  int gw = (blockIdx.x * 256 + tid) >> 6;   // 0..8191
  for (int row = gw; row < BB * NN; row += 8192) {
    const float4* xr = (const float4*)(x + (size_t)row * DD);
    float dq = 0.f, dkv = 0.f;
#pragma unroll
    for (int c = 0; c < 4; c++) {
      float4 xv = xr[c * 64 + lane];
      dq  += xv.x*wq4[c].x  + xv.y*wq4[c].y  + xv.z*wq4[c].z  + xv.w*wq4[c].w;
      dkv += xv.x*wkv4[c].x + xv.y*wkv4[c].y + xv.z*wkv4[c].z + xv.w*wkv4[c].w;
    }
#pragma unroll
    for (int off = 32; off > 0; off >>= 1) {
      dq  += __shfl_xor(dq, off);
      dkv += __shfl_xor(dkv, off);
    }
    if (lane == 0) { logq[row] = dq; logkv[row] = dkv; }
  }
}

// ---- merged: route2 (blocks 0..7) + weight transposes (8..1031) + out-fill (1032..1543) ----
// route2 occupies 8 CUs for ~25 us; wt (13 MB traffic) and fill (128 MB pure-write)
// run concurrently on the other 248 CUs — previously ~30 us of serial time.
// All three bodies are bit-identical re-indexings of the proven kernels.
__global__ __launch_bounds__(1024) void k_route2_plus(
    const float* __restrict__ logq_g, const float* __restrict__ logkv_g,
    float cq, float ckv,
    int* __restrict__ qtok, int* __restrict__ qmap,
    int* __restrict__ kvtok, int* __restrict__ kvmap,
    const float* __restrict__ wq_w, const float* __restrict__ wkv_w,
    const float* __restrict__ wout_w,
    short* __restrict__ wqT, short* __restrict__ wkvT, short* __restrict__ woutT,
    const float* __restrict__ nulltok, float* __restrict__ out)
{
  __shared__ float redf[2][16];
  __shared__ unsigned int hist[256];
  __shared__ int wsum[16];
  __shared__ int scal[2];
  __shared__ float twt[64][65];
  int bid0 = blockIdx.x;
  int tid = threadIdx.x;

  if (bid0 >= 1032) {
    // ---- out-fill branch: pure-write broadcast (512 blocks x 1024 thr, 16 iters) ----
    int t = (bid0 - 1032) * 1024 + tid;            // 0..524287
    float4 v = ((const float4*)nulltok)[t & 255];  // stride multiple of 256 -> invariant
    float4* o = (float4*)out;
    const size_t total = (size_t)BB * NN * DD / 4; // 8,388,608 float4s
    for (size_t i = t; i < total; i += 524288)
      o[i] = v;
    return;
  }
  if (bid0 >= 8) {
    // ---- weight-transpose branch: one 64x64 tile per block, 4 rows/thread ----
    int bid = bid0 - 8;
    const float* W; short* WT; int N, bx, by;
    if (bid < 256)      { W = wq_w;   WT = wqT;   N = 1024; bx = bid & 15;         by = bid >> 4; }
    else if (bid < 768) { W = wkv_w;  WT = wkvT;  N = 2048; bx = (bid - 256) & 31; by = (bid - 256) >> 5; }
    else                { W = wout_w; WT = woutT; N = 1024; bx = (bid - 768) & 15; by = (bid - 768) >> 4; }
    const int K = 1024;
    int n0 = bx * 64, k0 = by * 64;
    int c = tid & 63, r0 = (tid >> 6) * 4;
#pragma unroll
    for (int rr = 0; rr < 4; rr++)
      twt[r0 + rr][c] = W[(size_t)(k0 + r0 + rr) * N + n0 + c];
    __syncthreads();
#pragma unroll
    for (int rr = 0; rr < 4; rr++)
      WT[(size_t)(n0 + r0 + rr) * K + k0 + c] = f2bf(twt[c][r0 + rr]);
    return;
  }

  // ---- route2 branch (blocks 0..7), body unchanged ----
  int sel = bid0 >> 2, b = bid0 & 3;
  const float* logits = sel ? logkv_g : logq_g;
  int k = sel ? NKVc : NQc;
  float constant = sel ? ckv : cq;
  int* tok = sel ? kvtok : qtok;
  int* map = sel ? kvmap : qmap;
  int lane = tid & 63, wv = tid >> 6;
  const float4* lg = (const float4*)(logits + (size_t)b * NN);
  float s[8];
  float4 v0 = lg[tid * 2], v1 = lg[tid * 2 + 1];
  s[0]=v0.x; s[1]=v0.y; s[2]=v0.z; s[3]=v0.w;
  s[4]=v1.x; s[5]=v1.y; s[6]=v1.z; s[7]=v1.w;

  float m = s[0];
#pragma unroll
  for (int e = 1; e < 8; e++) m = fmaxf(m, s[e]);
#pragma unroll
  for (int off = 32; off > 0; off >>= 1) m = fmaxf(m, __shfl_xor(m, off));
  if (lane == 0) redf[0][wv] = m;
  __syncthreads();
  float maxs = redf[0][0];
  for (int i = 1; i < 16; i++) maxs = fmaxf(maxs, redf[0][i]);

  float a = constant - EPS_ * logf((float)NN);
  for (int it = 1; it < NITERS; it++) {
    float na = -a;
    float mm = fminf(maxs, na);
    float sum = 0.f;
#pragma unroll
    for (int e = 0; e < 8; e++) sum += expf((fminf(s[e], na) - mm) * (1.f / EPS_));
#pragma unroll
    for (int off = 32; off > 0; off >>= 1) sum += __shfl_xor(sum, off);
    if (lane == 0) redf[it & 1][wv] = sum;
    __syncthreads();
    float ss = redf[it & 1][0];
    for (int i = 1; i < 16; i++) ss += redf[it & 1][i];
    a = constant - mm - EPS_ * logf(ss);
  }

  u64 key[8];
#pragma unroll
  for (int e = 0; e < 8; e++) {
    int i = tid * 8 + e;
    float sc = expf(fminf(s[e] + a, 0.f) * (1.f / EPS_));
    key[e] = ((u64)__float_as_uint(sc) << 13) | (u64)(NN - 1 - i);
  }

  int kp = k;
  u64 pref = 0;
  for (int d = 5; d >= 0; d--) {
    int sh = d * 8;
    if (tid < 256) hist[tid] = 0;
    __syncthreads();
#pragma unroll
    for (int e = 0; e < 8; e++) {
      if ((key[e] >> (sh + 8)) == pref)
        atomicAdd(&hist[(unsigned)(key[e] >> sh) & 255u], 1u);
    }
    __syncthreads();
    if (wv == 0) {
      unsigned cc[4];
#pragma unroll
      for (int t = 0; t < 4; t++) cc[t] = hist[lane * 4 + t];
      unsigned g = cc[0] + cc[1] + cc[2] + cc[3];
      unsigned sfx = g;
#pragma unroll
      for (int off = 1; off < 64; off <<= 1) {
        unsigned t = __shfl_down(sfx, off);
        if (lane + off < 64) sfx += t;
      }
      unsigned aft0 = __shfl_down(sfx, 1);
      unsigned after = (lane == 63) ? 0u : aft0;
      if (sfx >= (unsigned)kp && after < (unsigned)kp) {
        unsigned above = after;
        int bin = 3;
        if (above + cc[3] < (unsigned)kp) { above += cc[3]; bin = 2;
          if (above + cc[2] < (unsigned)kp) { above += cc[2]; bin = 1;
            if (above + cc[1] < (unsigned)kp) { above += cc[1]; bin = 0; } } }
        scal[0] = lane * 4 + bin;
        scal[1] = kp - (int)above;
      }
    }
    __syncthreads();
    pref = (pref << 8) | (unsigned)scal[0];
    kp = scal[1];
  }
  u64 kth = pref;

  int flag[8], cnt = 0;
#pragma unroll
  for (int e = 0; e < 8; e++) { flag[e] = (key[e] >= kth) ? 1 : 0; cnt += flag[e]; }
  int incl = cnt;
#pragma unroll
  for (int off = 1; off < 64; off <<= 1) {
    int t3 = __shfl_up(incl, off);
    if (lane >= off) incl += t3;
  }
  if (lane == 63) wsum[wv] = incl;
  __syncthreads();
  int wbase = 0;
  for (int w2 = 0; w2 < wv; w2++) wbase += wsum[w2];
  int pos = wbase + incl - cnt;
  int bbase = b * k;
#pragma unroll
  for (int e = 0; e < 8; e++) {
    if (flag[e]) {
      int i = tid * 8 + e;
      tok[bbase + pos] = i;
      map[bbase + pos] = b * NN + i;
      pos++;
    }
  }
}

// ---------------- gather routed rows of x -> compact bf16 A matrix ----------------
__global__ __launch_bounds__(256) void k_gather(
    const float* __restrict__ x, const int* __restrict__ map, short* __restrict__ A)
{
  int row = blockIdx.x * 4 + (threadIdx.x >> 6);
  int lane = threadIdx.x & 63;
  int src = map[row];
  const float4* xr = (const float4*)(x + (size_t)src * DD);
  short4v* ar = (short4v*)(A + (size_t)row * DD);
#pragma unroll
  for (int c = 0; c < 4; c++) {
    float4 v = xr[c * 64 + lane];
    short4v s;
    s[0] = f2bf(v.x); s[1] = f2bf(v.y); s[2] = f2bf(v.z); s[3] = f2bf(v.w);
    ar[c * 64 + lane] = s;
  }
}

// ---------------- merged q-proj + kv-proj GEMM (1280 blocks, one launch) ----------------
// swz < 256: q-proj tile (8-wide grid, mode-1 epilogue); else kv-proj tile
// (16-wide grid, mode-2 epilogue). GEMM body identical to the proven round-3
// kernel; only the per-block pointer/geometry decode differs.
__global__ __launch_bounds__(256) void k_gemm_proj(
    const short* __restrict__ Aq, const short* __restrict__ wqT,
    const short* __restrict__ Akv, const short* __restrict__ wkvT,
    short* __restrict__ qhb, short* __restrict__ khb, short* __restrict__ vhbT)
{
  #define PBUF (128 * 32)
  __shared__ short As[2 * PBUF];
  __shared__ short Bs[2 * PBUF];
  const int Kdim = 1024;
  int tid = threadIdx.x;
  int lane = tid & 63, wv = tid >> 6;

  // XCD swizzle across the merged 1280-tile space (1280 % 8 == 0)
  int bid = blockIdx.x;
  int swz = (bid & 7) * 160 + (bid >> 3);
  const short* A; const short* BT; int mode, m0, n0;
  if (swz < 256) { A = Aq;  BT = wqT;  mode = 1; n0 = (swz & 7) * 128;  m0 = (swz >> 3) * 128; }
  else { int t2 = swz - 256; A = Akv; BT = wkvT; mode = 2; n0 = (t2 & 15) * 128; m0 = (t2 >> 4) * 128; }

  int wm = (wv >> 1) * 64, wn = (wv & 1) * 64;
  int fr = lane & 15, quad = lane >> 4;

  int c0 = wv * 128 + lane;
  int c1 = c0 + 64;
  const short* gA0 = A  + (size_t)(m0 + (c0 >> 2)) * Kdim + (c0 & 3) * 8;
  const short* gA1 = A  + (size_t)(m0 + (c1 >> 2)) * Kdim + (c1 & 3) * 8;
  const short* gB0 = BT + (size_t)(n0 + (c0 >> 2)) * Kdim + (c0 & 3) * 8;
  const short* gB1 = BT + (size_t)(n0 + (c1 >> 2)) * Kdim + (c1 & 3) * 8;
  short* lA0 = As + wv * 1024;
  short* lA1 = As + wv * 1024 + 512;
  short* lB0 = Bs + wv * 1024;
  short* lB1 = Bs + wv * 1024 + 512;

  f32x4 acc[4][4];
#pragma unroll
  for (int i = 0; i < 4; i++)
#pragma unroll
    for (int j = 0; j < 4; j++) {
      acc[i][j][0] = 0.f; acc[i][j][1] = 0.f; acc[i][j][2] = 0.f; acc[i][j][3] = 0.f;
    }

  GLOAD16(gA0, lA0);
  GLOAD16(gA1, lA1);
  GLOAD16(gB0, lB0);
  GLOAD16(gB1, lB1);
  __syncthreads();

  for (int k0 = 0; k0 < Kdim; k0 += 32) {
    int cur = (k0 >> 5) & 1, nxt = cur ^ 1;
    if (k0 + 32 < Kdim) {
      GLOAD16(gA0 + k0 + 32, lA0 + nxt * PBUF);
      GLOAD16(gA1 + k0 + 32, lA1 + nxt * PBUF);
      GLOAD16(gB0 + k0 + 32, lB0 + nxt * PBUF);
      GLOAD16(gB1 + k0 + 32, lB1 + nxt * PBUF);
    }
    const short* Ab = As + cur * PBUF;
    const short* Bb = Bs + cur * PBUF;
    bfrag8 af[4], bf[4];
#pragma unroll
    for (int t = 0; t < 4; t++) {
      af[t] = *(const bfrag8*)&Ab[(wm + t * 16 + fr) * 32 + quad * 8];
      bf[t] = *(const bfrag8*)&Bb[(wn + t * 16 + fr) * 32 + quad * 8];
    }
#pragma unroll
    for (int mt = 0; mt < 4; mt++)
#pragma unroll
      for (int nt = 0; nt < 4; nt++)
        acc[mt][nt] = MFMA_BF16(af[mt], bf[nt], acc[mt][nt]);
    __syncthreads();
  }

#pragma unroll
  for (int mt = 0; mt < 4; mt++) {
#pragma unroll
    for (int nt = 0; nt < 4; nt++) {
#pragma unroll
      for (int r = 0; r < 4; r++) {
        int grow = m0 + wm + mt * 16 + quad * 4 + r;
        int gcol = n0 + wn + nt * 16 + fr;
        float v = acc[mt][nt][r];
        if (mode == 1) {
          int b = grow >> 10, q = grow & 1023;
          int h = gcol >> 6, d = gcol & 63;
          qhb[((size_t)(b * HH + h) * NQc + q) * DHH + d] = f2bf(v);
        } else {
          int b = grow >> 11, t = grow & 2047;
          if (gcol < 1024) {
            int h = gcol >> 6, d = gcol & 63;
            khb[((size_t)(b * HH + h) * NKVc + t) * DHH + d] = f2bf(v);
          } else {
            int c2 = gcol - 1024, h = c2 >> 6, d = c2 & 63;
            vhbT[((size_t)(b * HH + h) * DHH + d) * NKVc + t] = f2bf(v);
          }
        }
      }
    }
  }
  #undef PBUF
}

// ---------------- out-proj GEMM (mode-0 scatter), round-3 proven body ----------------
__global__ __launch_bounds__(256) void k_gemm_out(
    const short* __restrict__ A, const short* __restrict__ BT,
    float* __restrict__ Cf, const int* __restrict__ rowmapC)
{
  #define PBUF (128 * 32)
  __shared__ short As[2 * PBUF];
  __shared__ short Bs[2 * PBUF];
  const int Kdim = 1024;
  int tid = threadIdx.x;
  int lane = tid & 63, wv = tid >> 6;

  int nwg = gridDim.x * gridDim.y;
  int bid = blockIdx.y * gridDim.x + blockIdx.x;
  int cpx = nwg >> 3;
  int swz = (bid & 7) * cpx + (bid >> 3);
  int m0 = (swz / gridDim.x) * 128, n0 = (swz % gridDim.x) * 128;

  int wm = (wv >> 1) * 64, wn = (wv & 1) * 64;
  int fr = lane & 15, quad = lane >> 4;

  int c0 = wv * 128 + lane;
  int c1 = c0 + 64;
  const short* gA0 = A  + (size_t)(m0 + (c0 >> 2)) * Kdim + (c0 & 3) * 8;
  const short* gA1 = A  + (size_t)(m0 + (c1 >> 2)) * Kdim + (c1 & 3) * 8;
  const short* gB0 = BT + (size_t)(n0 + (c0 >> 2)) * Kdim + (c0 & 3) * 8;
  const short* gB1 = BT + (size_t)(n0 + (c1 >> 2)) * Kdim + (c1 & 3) * 8;
  short* lA0 = As + wv * 1024;
  short* lA1 = As + wv * 1024 + 512;
  short* lB0 = Bs + wv * 1024;
  short* lB1 = Bs + wv * 1024 + 512;

  f32x4 acc[4][4];
#pragma unroll
  for (int i = 0; i < 4; i++)
#pragma unroll
    for (int j = 0; j < 4; j++) {
      acc[i][j][0] = 0.f; acc[i][j][1] = 0.f; acc[i][j][2] = 0.f; acc[i][j][3] = 0.f;
    }

  GLOAD16(gA0, lA0);
  GLOAD16(gA1, lA1);
  GLOAD16(gB0, lB0);
  GLOAD16(gB1, lB1);
  __syncthreads();

  for (int k0 = 0; k0 < Kdim; k0 += 32) {
    int cur = (k0 >> 5) & 1, nxt = cur ^ 1;
    if (k0 + 32 < Kdim) {
      GLOAD16(gA0 + k0 + 32, lA0 + nxt * PBUF);
      GLOAD16(gA1 + k0 + 32, lA1 + nxt * PBUF);
      GLOAD16(gB0 + k0 + 32, lB0 + nxt * PBUF);
      GLOAD16(gB1 + k0 + 32, lB1 + nxt * PBUF);
    }
    const short* Ab = As + cur * PBUF;
    const short* Bb = Bs + cur * PBUF;
    bfrag8 af[4], bf[4];
#pragma unroll
    for (int t = 0; t < 4; t++) {
      af[t] = *(const bfrag8*)&Ab[(wm + t * 16 + fr) * 32 + quad * 8];
      bf[t] = *(const bfrag8*)&Bb[(wn + t * 16 + fr) * 32 + quad * 8];
    }
#pragma unroll
    for (int mt = 0; mt < 4; mt++)
#pragma unroll
      for (int nt = 0; nt < 4; nt++)
        acc[mt][nt] = MFMA_BF16(af[mt], bf[nt], acc[mt][nt]);
    __syncthreads();
  }

#pragma unroll
  for (int mt = 0; mt < 4; mt++)
#pragma unroll
    for (int nt = 0; nt < 4; nt++)
#pragma unroll
      for (int r = 0; r < 4; r++) {
        int grow = m0 + wm + mt * 16 + quad * 4 + r;
        int gcol = n0 + wn + nt * 16 + fr;
        int gr = rowmapC[grow];
        Cf[(size_t)gr * 1024 + gcol] = acc[mt][nt][r];
      }
  #undef PBUF
}

// ---------------- merged rotary (q blocks 0..16383, k blocks 16384..49151) ----------------
__global__ __launch_bounds__(256) void k_rot(
    short* __restrict__ qhb, short* __restrict__ khb,
    const float* __restrict__ rotary,
    const int* __restrict__ qtok, const int* __restrict__ kvtok)
{
  int bid = blockIdx.x;
  int lane = threadIdx.x & 63;
  if (bid < 16384) {
    int gw = (bid * 256 + threadIdx.x) >> 6;
    int b = gw >> 14, rem = gw & 16383, h = rem >> 10, q = rem & 1023;
    int tokid = qtok[b * NQc + q];
    float p = rotary[(size_t)tokid * DHH + lane];
    size_t base = ((size_t)(b * HH + h) * NQc + q) * DHH;
    float t = bf2f(qhb[base + lane]);
    float partner = __shfl_xor(t, 32);
    float rh = (lane < 32) ? -partner : partner;
    qhb[base + lane] = f2bf((t * cosf(p) + rh * sinf(p)) * 0.125f);
  } else {
    int gw = ((bid - 16384) * 256 + threadIdx.x) >> 6;
    int b = gw >> 15, rem = gw & 32767, h = rem >> 11, j = rem & 2047;
    int tokid = kvtok[b * NKVc + j];
    float p = rotary[(size_t)tokid * DHH + lane];
    size_t base = ((size_t)(b * HH + h) * NKVc + j) * DHH;
    float t = bf2f(khb[base + lane]);
    float partner = __shfl_xor(t, 32);
    float rh = (lane < 32) ? -partner : partner;
    khb[base + lane] = f2bf(t * cosf(p) + rh * sinf(p));
  }
}

// ---------------- MFMA flash attention (bf16 in, bf16 out) ----------------
#define KP 72    // K/V row pitch (shorts): 144 B -> 2-way frag reads (free)
#define PP2 72   // P row pitch (shorts)
__global__ __launch_bounds__(256) void k_attn_mfma(
    const short* __restrict__ qhb, const short* __restrict__ khb,
    const short* __restrict__ vhbT, const float* __restrict__ nullkv,
    short* __restrict__ attnb)
{
  __shared__ short Kt[2][64][KP];    // [buf][key][d]
  __shared__ short Vt[2][64][KP];    // [buf][d][key]
  __shared__ short Pb[4][16][PP2];   // per-wave P: [q(16)][key(64)]
  int tid = threadIdx.x;
  int lane = tid & 63, wv = tid >> 6;
  int bid = blockIdx.x;
  int xcd = bid & 7, j = bid >> 3;
  int bh = xcd * 8 + (j & 7);
  int qb = j >> 3;
  int q0 = qb * 128 + wv * 32;
  int fr = lane & 15, quad = lane >> 4;
  int b = bh >> 4, h = bh & 15;

  bfrag8 onesf;
#pragma unroll
  for (int e = 0; e < 8; e++) onesf[e] = (short)0x3F80;   // bf16 1.0

  bfrag8 qf[2][2];
#pragma unroll
  for (int qg = 0; qg < 2; qg++) {
    const short* qbase = qhb + ((size_t)bh * NQc + q0 + qg * 16 + fr) * DHH + quad * 8;
    qf[qg][0] = *(const bfrag8*)(qbase);
    qf[qg][1] = *(const bfrag8*)(qbase + 32);
  }

  float sn[2];
#pragma unroll
  for (int qg = 0; qg < 2; qg++) {
    float accn = 0.f;
#pragma unroll
    for (int e = 0; e < 8; e++) {
      accn += bf2f(qf[qg][0][e]) * nullkv[h * DHH + quad * 8 + e];
      accn += bf2f(qf[qg][1][e]) * nullkv[h * DHH + 32 + quad * 8 + e];
    }
    accn += __shfl_xor(accn, 16);
    accn += __shfl_xor(accn, 32);
    sn[qg] = accn;
  }
  float vn[4];
#pragma unroll
  for (int g = 0; g < 4; g++) vn[g] = nullkv[(HH + h) * DHH + g * 16 + fr];

  f32x4 o[2][4], l4[2];
#pragma unroll
  for (int qg = 0; qg < 2; qg++) {
#pragma unroll
    for (int g = 0; g < 4; g++) {
      o[qg][g][0]=0.f; o[qg][g][1]=0.f; o[qg][g][2]=0.f; o[qg][g][3]=0.f;
    }
    l4[qg][0]=0.f; l4[qg][1]=0.f; l4[qg][2]=0.f; l4[qg][3]=0.f;
  }

  int rr = tid >> 3, ch8 = (tid & 7) * 8;
  const short* kp0 = khb + (size_t)bh * NKVc * DHH + (size_t)rr * DHH + ch8;
  const short* kp1 = kp0 + 32 * DHH;
  const short* vp0 = vhbT + ((size_t)bh * DHH + rr) * NKVc + ch8;
  const short* vp1 = vp0 + (size_t)32 * NKVc;

  bfrag8 kr0 = *(const bfrag8*)kp0;
  bfrag8 kr1 = *(const bfrag8*)kp1;
  bfrag8 vr0 = *(const bfrag8*)vp0;
  bfrag8 vr1 = *(const bfrag8*)vp1;

  for (int t = 0; t < 32; t++) {
    int cur = t & 1;
    *(bfrag8*)&Kt[cur][rr][ch8]      = kr0;
    *(bfrag8*)&Kt[cur][rr + 32][ch8] = kr1;
    *(bfrag8*)&Vt[cur][rr][ch8]      = vr0;
    *(bfrag8*)&Vt[cur][rr + 32][ch8] = vr1;
    if (t < 31) {
      size_t ko = (size_t)(t + 1) * 64 * DHH;
      size_t vo = (size_t)(t + 1) * 64;
      kr0 = *(const bfrag8*)(kp0 + ko);
      kr1 = *(const bfrag8*)(kp1 + ko);
      vr0 = *(const bfrag8*)(vp0 + vo);
      vr1 = *(const bfrag8*)(vp1 + vo);
    }
    __builtin_amdgcn_sched_barrier(0);
    asm volatile("s_waitcnt lgkmcnt(0)" ::: "memory");
    __builtin_amdgcn_s_barrier();
    __builtin_amdgcn_sched_barrier(0);

    bfrag8 kf[4][2], vf[4][2];
#pragma unroll
    for (int g = 0; g < 4; g++) {
      kf[g][0] = *(const bfrag8*)&Kt[cur][g * 16 + fr][quad * 8];
      kf[g][1] = *(const bfrag8*)&Kt[cur][g * 16 + fr][32 + quad * 8];
      vf[g][0] = *(const bfrag8*)&Vt[cur][g * 16 + fr][quad * 8];
      vf[g][1] = *(const bfrag8*)&Vt[cur][g * 16 + fr][32 + quad * 8];
    }

#pragma unroll
    for (int qg = 0; qg < 2; qg++) {
      f32x4 sa[4];
#pragma unroll
      for (int g = 0; g < 4; g++) { sa[g][0]=0.f; sa[g][1]=0.f; sa[g][2]=0.f; sa[g][3]=0.f; }
#pragma unroll
      for (int g = 0; g < 4; g++) {
        sa[g] = MFMA_BF16(kf[g][0], qf[qg][0], sa[g]);
        sa[g] = MFMA_BF16(kf[g][1], qf[qg][1], sa[g]);
      }
#pragma unroll
      for (int g = 0; g < 4; g++) {
        short4v p4;
#pragma unroll
        for (int r = 0; r < 4; r++) p4[r] = f2bf_fast(__expf(sa[g][r]));
        *(short4v*)&Pb[wv][fr][g * 16 + quad * 4] = p4;
      }
      bfrag8 pf0 = *(const bfrag8*)&Pb[wv][fr][quad * 8];
      bfrag8 pf1 = *(const bfrag8*)&Pb[wv][fr][32 + quad * 8];
      l4[qg] = MFMA_BF16(pf0, onesf, l4[qg]);
      l4[qg] = MFMA_BF16(pf1, onesf, l4[qg]);
#pragma unroll
      for (int g = 0; g < 4; g++) {
        o[qg][g] = MFMA_BF16(pf0, vf[g][0], o[qg][g]);
        o[qg][g] = MFMA_BF16(pf1, vf[g][1], o[qg][g]);
      }
    }
  }

#pragma unroll
  for (int qg = 0; qg < 2; qg++) {
    float pn[4];
#pragma unroll
    for (int r = 0; r < 4; r++) {
      pn[r] = __expf(__shfl(sn[qg], quad * 4 + r));
      l4[qg][r] += pn[r];
    }
#pragma unroll
    for (int g = 0; g < 4; g++)
#pragma unroll
      for (int r = 0; r < 4; r++)
        o[qg][g][r] += pn[r] * vn[g];
  }
#pragma unroll
  for (int qg = 0; qg < 2; qg++) {
    float inv[4];
#pragma unroll
    for (int r = 0; r < 4; r++) inv[r] = 1.f / l4[qg][r];
#pragma unroll
    for (int r = 0; r < 4; r++) {
      size_t row = (size_t)(b * NQc + q0 + qg * 16 + quad * 4 + r) * DD + h * DHH;
#pragma unroll
      for (int g = 0; g < 4; g++)
        attnb[row + g * 16 + fr] = f2bf(o[qg][g][r] * inv[r]);
    }
  }
}

extern "C" void kernel_launch(void* const* d_in, const int* in_sizes, int n_in,
                              void* d_out, int out_size, void* d_ws, size_t ws_size,
                              hipStream_t stream)
{
  const float* x       = (const float*)d_in[0];
  const float* rotary  = (const float*)d_in[1];
  const float* wrq     = (const float*)d_in[2];
  const float* wrkv    = (const float*)d_in[3];
  const float* wq      = (const float*)d_in[4];
  const float* wkv     = (const float*)d_in[5];
  const float* wout    = (const float*)d_in[6];
  const float* nullkv  = (const float*)d_in[7];
  const float* nulltok = (const float*)d_in[8];
  float* out = (float*)d_out;
  float* ws  = (float*)d_ws;

  // workspace (float offsets), total 21,061,632 floats ~ 84.25 MB (round-3 proven)
  float* logq  = ws;                  // 32768
  float* logkv = ws + 32768;          // 32768
  int*   qtok  = (int*)(ws + 65536);  // 4096
  int*   kvtok = (int*)(ws + 69632);  // 8192
  int*   qmap  = (int*)(ws + 77824);  // 4096 (kvmap contiguous after — k_gather relies on it)
  int*   kvmap = (int*)(ws + 81920);  // 8192 -> 90112
  short* qhb   = (short*)(ws + 90112);     // 4,194,304 sh -> 2,187,264
  short* khb   = (short*)(ws + 2187264);   // 8,388,608 sh -> 6,381,568
  short* vhbT  = (short*)(ws + 6381568);   // 8,388,608 sh -> 10,575,872
  short* attnb = (short*)(ws + 10575872);  // 4,194,304 sh -> 12,673,024
  short* Aq    = (short*)(ws + 12673024);  // 4096*1024 sh (Akv contiguous after)
  short* wqT   = (short*)(ws + 18964480);  // 1024*1024 sh -> 19,488,768
  short* wkvT  = (short*)(ws + 19488768);  // 2048*1024 sh -> 20,537,344
  short* woutT = (short*)(ws + 20537344);  // 1024*1024 sh -> 21,061,632
  short* Akv   = Aq + (size_t)4096 * 1024;

  k_logits<<<2048, 256, 0, stream>>>(x, wrq, wrkv, logq, logkv);
  // route2 (8 blocks) + weight transposes (1024) + out base-fill (512) in ONE launch:
  // wt/fill run on the 248 CUs route2 leaves idle.
  k_route2_plus<<<1544, 1024, 0, stream>>>(
      logq, logkv, 0.1f * logf(1152.f), 0.1f * logf(2304.f),
      qtok, qmap, kvtok, kvmap,
      wq, wkv, wout, wqT, wkvT, woutT, nulltok, out);
  k_gather<<<3072, 256, 0, stream>>>(x, qmap, Aq);   // covers Aq AND Akv
  // q proj + kv proj in ONE launch (256 + 1024 tiles)
  k_gemm_proj<<<1280, 256, 0, stream>>>(Aq, wqT, Akv, wkvT, qhb, khb, vhbT);
  // q rotary + k rotary in ONE launch
  k_rot<<<49152, 256, 0, stream>>>(qhb, khb, rotary, qtok, kvtok);
  k_attn_mfma<<<512, 256, 0, stream>>>(qhb, khb, vhbT, nullkv, attnb);
  // out proj: M=4096 N=1024, scatter rows via qmap (out already base-filled)
  k_gemm_out<<<dim3(8, 32), 256, 0, stream>>>(attnb, woutT, out, qmap);
}

// Round 10
// 473.266 us; speedup vs baseline: 1.1272x; 1.0052x over previous
//
#include <hip/hip_runtime.h>
#include <stdint.h>
#include <math.h>

#define BB 4
#define NN 8192
#define DD 1024
#define HH 16
#define DHH 64
#define NQc 1024
#define NKVc 2048
#define EPS_ 0.1f
#define NITERS 20

typedef unsigned long long u64;
typedef __attribute__((ext_vector_type(8))) short bfrag8;   // 8 bf16 = 4 VGPRs (MFMA A/B)
typedef __attribute__((ext_vector_type(4))) float f32x4;    // MFMA C/D
typedef __attribute__((ext_vector_type(4))) short short4v;

#define MFMA_BF16(a, b, c) __builtin_amdgcn_mfma_f32_16x16x32_bf16(a, b, c, 0, 0, 0)

// async global->LDS, 16B per lane; LDS dest = wave-uniform base + lane*16
#define GLOAD16(gp, lp) __builtin_amdgcn_global_load_lds( \
    (const __attribute__((address_space(1))) void*)(gp),  \
    (__attribute__((address_space(3))) void*)(lp), 16, 0, 0)

static __device__ inline short f2bf(float f) {
  uint32_t u = __float_as_uint(f);
  uint32_t r = (u + 0x7fffu + ((u >> 16) & 1u)) >> 16;   // round-to-nearest-even
  return (short)r;
}
static __device__ inline short f2bf_fast(float f) {       // round-half-up (2 inst)
  return (short)((__float_as_uint(f) + 0x8000u) >> 16);
}
static __device__ inline float bf2f(short s) {
  return __uint_as_float(((uint32_t)(uint16_t)s) << 16);
}

// ---------------- router logits: PURE-READ stream, weights in registers ----------------
__global__ __launch_bounds__(256) void k_logits(
    const float* __restrict__ x, const float* __restrict__ wq,
    const float* __restrict__ wkv,
    float* __restrict__ logq, float* __restrict__ logkv)
{
  int tid = threadIdx.x;
  int lane = tid & 63;
  float4 wq4[4], wkv4[4];
#pragma unroll
  for (int c = 0; c < 4; c++) {
    wq4[c]  = ((const float4*)wq)[c * 64 + lane];
    wkv4[c] = ((const float4*)wkv)[c * 64 + lane];
  }
  int gw = (blockIdx.x * 256 + tid) >> 6;   // 0..8191
  for (int row = gw; row < BB * NN; row += 8192) {
    const float4* xr = (const float4*)(x + (size_t)row * DD);
    float dq = 0.f, dkv = 0.f;
#pragma unroll
    for (int c = 0; c < 4; c++) {
      float4 xv = xr[c * 64 + lane];
      dq  += xv.x*wq4[c].x  + xv.y*wq4[c].y  + xv.z*wq4[c].z  + xv.w*wq4[c].w;
      dkv += xv.x*wkv4[c].x + xv.y*wkv4[c].y + xv.z*wkv4[c].z + xv.w*wkv4[c].w;
    }
#pragma unroll
    for (int off = 32; off > 0; off >>= 1) {
      dq  += __shfl_xor(dq, off);
      dkv += __shfl_xor(dkv, off);
    }
    if (lane == 0) { logq[row] = dq; logkv[row] = dkv; }
  }
}

// ---- merged: route2 (blocks 0..7) + weight transposes (8..1031) + out-fill (1032..1543) ----
__global__ __launch_bounds__(1024) void k_route2_plus(
    const float* __restrict__ logq_g, const float* __restrict__ logkv_g,
    float cq, float ckv,
    int* __restrict__ qtok, int* __restrict__ qmap,
    int* __restrict__ kvtok, int* __restrict__ kvmap,
    const float* __restrict__ wq_w, const float* __restrict__ wkv_w,
    const float* __restrict__ wout_w,
    short* __restrict__ wqT, short* __restrict__ wkvT, short* __restrict__ woutT,
    const float* __restrict__ nulltok, float* __restrict__ out)
{
  __shared__ float redf[2][16];
  __shared__ unsigned int hist[256];
  __shared__ int wsum[16];
  __shared__ int scal[2];
  __shared__ float twt[64][65];
  int bid0 = blockIdx.x;
  int tid = threadIdx.x;

  if (bid0 >= 1032) {
    // ---- out-fill branch: pure-write broadcast (512 blocks x 1024 thr, 16 iters) ----
    int t = (bid0 - 1032) * 1024 + tid;            // 0..524287
    float4 v = ((const float4*)nulltok)[t & 255];  // stride multiple of 256 -> invariant
    float4* o = (float4*)out;
    const size_t total = (size_t)BB * NN * DD / 4; // 8,388,608 float4s
    for (size_t i = t; i < total; i += 524288)
      o[i] = v;
    return;
  }
  if (bid0 >= 8) {
    // ---- weight-transpose branch: one 64x64 tile per block, 4 rows/thread ----
    int bid = bid0 - 8;
    const float* W; short* WT; int N, bx, by;
    if (bid < 256)      { W = wq_w;   WT = wqT;   N = 1024; bx = bid & 15;         by = bid >> 4; }
    else if (bid < 768) { W = wkv_w;  WT = wkvT;  N = 2048; bx = (bid - 256) & 31; by = (bid - 256) >> 5; }
    else                { W = wout_w; WT = woutT; N = 1024; bx = (bid - 768) & 15; by = (bid - 768) >> 4; }
    const int K = 1024;
    int n0 = bx * 64, k0 = by * 64;
    int c = tid & 63, r0 = (tid >> 6) * 4;
#pragma unroll
    for (int rr = 0; rr < 4; rr++)
      twt[r0 + rr][c] = W[(size_t)(k0 + r0 + rr) * N + n0 + c];
    __syncthreads();
#pragma unroll
    for (int rr = 0; rr < 4; rr++)
      WT[(size_t)(n0 + r0 + rr) * K + k0 + c] = f2bf(twt[c][r0 + rr]);
    return;
  }

  // ---- route2 branch (blocks 0..7), body unchanged ----
  int sel = bid0 >> 2, b = bid0 & 3;
  const float* logits = sel ? logkv_g : logq_g;
  int k = sel ? NKVc : NQc;
  float constant = sel ? ckv : cq;
  int* tok = sel ? kvtok : qtok;
  int* map = sel ? kvmap : qmap;
  int lane = tid & 63, wv = tid >> 6;
  const float4* lg = (const float4*)(logits + (size_t)b * NN);
  float s[8];
  float4 v0 = lg[tid * 2], v1 = lg[tid * 2 + 1];
  s[0]=v0.x; s[1]=v0.y; s[2]=v0.z; s[3]=v0.w;
  s[4]=v1.x; s[5]=v1.y; s[6]=v1.z; s[7]=v1.w;

  float m = s[0];
#pragma unroll
  for (int e = 1; e < 8; e++) m = fmaxf(m, s[e]);
#pragma unroll
  for (int off = 32; off > 0; off >>= 1) m = fmaxf(m, __shfl_xor(m, off));
  if (lane == 0) redf[0][wv] = m;
  __syncthreads();
  float maxs = redf[0][0];
  for (int i = 1; i < 16; i++) maxs = fmaxf(maxs, redf[0][i]);

  float a = constant - EPS_ * logf((float)NN);
  for (int it = 1; it < NITERS; it++) {
    float na = -a;
    float mm = fminf(maxs, na);
    float sum = 0.f;
#pragma unroll
    for (int e = 0; e < 8; e++) sum += expf((fminf(s[e], na) - mm) * (1.f / EPS_));
#pragma unroll
    for (int off = 32; off > 0; off >>= 1) sum += __shfl_xor(sum, off);
    if (lane == 0) redf[it & 1][wv] = sum;
    __syncthreads();
    float ss = redf[it & 1][0];
    for (int i = 1; i < 16; i++) ss += redf[it & 1][i];
    a = constant - mm - EPS_ * logf(ss);
  }

  u64 key[8];
#pragma unroll
  for (int e = 0; e < 8; e++) {
    int i = tid * 8 + e;
    float sc = expf(fminf(s[e] + a, 0.f) * (1.f / EPS_));
    key[e] = ((u64)__float_as_uint(sc) << 13) | (u64)(NN - 1 - i);
  }

  int kp = k;
  u64 pref = 0;
  for (int d = 5; d >= 0; d--) {
    int sh = d * 8;
    if (tid < 256) hist[tid] = 0;
    __syncthreads();
#pragma unroll
    for (int e = 0; e < 8; e++) {
      if ((key[e] >> (sh + 8)) == pref)
        atomicAdd(&hist[(unsigned)(key[e] >> sh) & 255u], 1u);
    }
    __syncthreads();
    if (wv == 0) {
      unsigned cc[4];
#pragma unroll
      for (int t = 0; t < 4; t++) cc[t] = hist[lane * 4 + t];
      unsigned g = cc[0] + cc[1] + cc[2] + cc[3];
      unsigned sfx = g;
#pragma unroll
      for (int off = 1; off < 64; off <<= 1) {
        unsigned t = __shfl_down(sfx, off);
        if (lane + off < 64) sfx += t;
      }
      unsigned aft0 = __shfl_down(sfx, 1);
      unsigned after = (lane == 63) ? 0u : aft0;
      if (sfx >= (unsigned)kp && after < (unsigned)kp) {
        unsigned above = after;
        int bin = 3;
        if (above + cc[3] < (unsigned)kp) { above += cc[3]; bin = 2;
          if (above + cc[2] < (unsigned)kp) { above += cc[2]; bin = 1;
            if (above + cc[1] < (unsigned)kp) { above += cc[1]; bin = 0; } } }
        scal[0] = lane * 4 + bin;
        scal[1] = kp - (int)above;
      }
    }
    __syncthreads();
    pref = (pref << 8) | (unsigned)scal[0];
    kp = scal[1];
  }
  u64 kth = pref;

  int flag[8], cnt = 0;
#pragma unroll
  for (int e = 0; e < 8; e++) { flag[e] = (key[e] >= kth) ? 1 : 0; cnt += flag[e]; }
  int incl = cnt;
#pragma unroll
  for (int off = 1; off < 64; off <<= 1) {
    int t3 = __shfl_up(incl, off);
    if (lane >= off) incl += t3;
  }
  if (lane == 63) wsum[wv] = incl;
  __syncthreads();
  int wbase = 0;
  for (int w2 = 0; w2 < wv; w2++) wbase += wsum[w2];
  int pos = wbase + incl - cnt;
  int bbase = b * k;
#pragma unroll
  for (int e = 0; e < 8; e++) {
    if (flag[e]) {
      int i = tid * 8 + e;
      tok[bbase + pos] = i;
      map[bbase + pos] = b * NN + i;
      pos++;
    }
  }
}

// ---------------- gather routed rows of x -> compact bf16 A matrix ----------------
__global__ __launch_bounds__(256) void k_gather(
    const float* __restrict__ x, const int* __restrict__ map, short* __restrict__ A)
{
  int row = blockIdx.x * 4 + (threadIdx.x >> 6);
  int lane = threadIdx.x & 63;
  int src = map[row];
  const float4* xr = (const float4*)(x + (size_t)src * DD);
  short4v* ar = (short4v*)(A + (size_t)row * DD);
#pragma unroll
  for (int c = 0; c < 4; c++) {
    float4 v = xr[c * 64 + lane];
    short4v s;
    s[0] = f2bf(v.x); s[1] = f2bf(v.y); s[2] = f2bf(v.z); s[3] = f2bf(v.w);
    ar[c * 64 + lane] = s;
  }
}

// 3-buffer, 2-tile-deep counted-vmcnt K-pipeline (T3/T4): tile t computes while
// t+1, t+2 loads fly. s_waitcnt vmcnt(4) drains ONLY tile t; never 0 mid-loop.
// Hazard: buf (t+2)%3's prior readers retired via lgkmcnt(0)+barrier before issue.
#define GEMM_PIPE_LOOP(EPILOGUE_DECODE)                                        \
  GLOAD16(gA0, lA0);                                                           \
  GLOAD16(gA1, lA1);                                                           \
  GLOAD16(gB0, lB0);                                                           \
  GLOAD16(gB1, lB1);                                                           \
  GLOAD16(gA0 + 32, lA0 + PBUF);                                               \
  GLOAD16(gA1 + 32, lA1 + PBUF);                                               \
  GLOAD16(gB0 + 32, lB0 + PBUF);                                               \
  GLOAD16(gB1 + 32, lB1 + PBUF);                                               \
  for (int t = 0; t < 32; t++) {                                               \
    if (t < 31) { asm volatile("s_waitcnt vmcnt(4)" ::: "memory"); }           \
    else        { asm volatile("s_waitcnt vmcnt(0)" ::: "memory"); }           \
    asm volatile("s_waitcnt lgkmcnt(0)" ::: "memory");                         \
    __builtin_amdgcn_s_barrier();                                              \
    __builtin_amdgcn_sched_barrier(0);                                         \
    if (t + 2 < 32) {                                                          \
      int nb = (t + 2) % 3;                                                    \
      int ko = (t + 2) * 32;                                                   \
      GLOAD16(gA0 + ko, lA0 + nb * PBUF);                                      \
      GLOAD16(gA1 + ko, lA1 + nb * PBUF);                                      \
      GLOAD16(gB0 + ko, lB0 + nb * PBUF);                                      \
      GLOAD16(gB1 + ko, lB1 + nb * PBUF);                                      \
    }                                                                          \
    int cb = t % 3;                                                            \
    const short* Ab = As + cb * PBUF;                                          \
    const short* Bb = Bs + cb * PBUF;                                          \
    bfrag8 af[4], bf[4];                                                       \
    _Pragma("unroll")                                                          \
    for (int tt = 0; tt < 4; tt++) {                                           \
      af[tt] = *(const bfrag8*)&Ab[(wm + tt * 16 + fr) * 32 + quad * 8];       \
      bf[tt] = *(const bfrag8*)&Bb[(wn + tt * 16 + fr) * 32 + quad * 8];       \
    }                                                                          \
    _Pragma("unroll")                                                          \
    for (int mt = 0; mt < 4; mt++)                                             \
      _Pragma("unroll")                                                        \
      for (int nt = 0; nt < 4; nt++)                                           \
        acc[mt][nt] = MFMA_BF16(af[mt], bf[nt], acc[mt][nt]);                  \
  }

// ---------------- merged q-proj + kv-proj GEMM (1280 blocks, one launch) ----------------
__global__ __launch_bounds__(256) void k_gemm_proj(
    const short* __restrict__ Aq, const short* __restrict__ wqT,
    const short* __restrict__ Akv, const short* __restrict__ wkvT,
    short* __restrict__ qhb, short* __restrict__ khb, short* __restrict__ vhbT)
{
  #define PBUF (128 * 32)
  __shared__ short As[3 * PBUF];
  __shared__ short Bs[3 * PBUF];
  const int Kdim = 1024;
  int tid = threadIdx.x;
  int lane = tid & 63, wv = tid >> 6;

  // XCD swizzle across the merged 1280-tile space (1280 % 8 == 0)
  int bid = blockIdx.x;
  int swz = (bid & 7) * 160 + (bid >> 3);
  const short* A; const short* BT; int mode, m0, n0;
  if (swz < 256) { A = Aq;  BT = wqT;  mode = 1; n0 = (swz & 7) * 128;  m0 = (swz >> 3) * 128; }
  else { int t2 = swz - 256; A = Akv; BT = wkvT; mode = 2; n0 = (t2 & 15) * 128; m0 = (t2 >> 4) * 128; }

  int wm = (wv >> 1) * 64, wn = (wv & 1) * 64;
  int fr = lane & 15, quad = lane >> 4;

  int c0 = wv * 128 + lane;
  int c1 = c0 + 64;
  const short* gA0 = A  + (size_t)(m0 + (c0 >> 2)) * Kdim + (c0 & 3) * 8;
  const short* gA1 = A  + (size_t)(m0 + (c1 >> 2)) * Kdim + (c1 & 3) * 8;
  const short* gB0 = BT + (size_t)(n0 + (c0 >> 2)) * Kdim + (c0 & 3) * 8;
  const short* gB1 = BT + (size_t)(n0 + (c1 >> 2)) * Kdim + (c1 & 3) * 8;
  short* lA0 = As + wv * 1024;
  short* lA1 = As + wv * 1024 + 512;
  short* lB0 = Bs + wv * 1024;
  short* lB1 = Bs + wv * 1024 + 512;

  f32x4 acc[4][4];
#pragma unroll
  for (int i = 0; i < 4; i++)
#pragma unroll
    for (int j = 0; j < 4; j++) {
      acc[i][j][0] = 0.f; acc[i][j][1] = 0.f; acc[i][j][2] = 0.f; acc[i][j][3] = 0.f;
    }

  GEMM_PIPE_LOOP()

#pragma unroll
  for (int mt = 0; mt < 4; mt++) {
#pragma unroll
    for (int nt = 0; nt < 4; nt++) {
#pragma unroll
      for (int r = 0; r < 4; r++) {
        int grow = m0 + wm + mt * 16 + quad * 4 + r;
        int gcol = n0 + wn + nt * 16 + fr;
        float v = acc[mt][nt][r];
        if (mode == 1) {
          int b = grow >> 10, q = grow & 1023;
          int h = gcol >> 6, d = gcol & 63;
          qhb[((size_t)(b * HH + h) * NQc + q) * DHH + d] = f2bf(v);
        } else {
          int b = grow >> 11, t = grow & 2047;
          if (gcol < 1024) {
            int h = gcol >> 6, d = gcol & 63;
            khb[((size_t)(b * HH + h) * NKVc + t) * DHH + d] = f2bf(v);
          } else {
            int c2 = gcol - 1024, h = c2 >> 6, d = c2 & 63;
            vhbT[((size_t)(b * HH + h) * DHH + d) * NKVc + t] = f2bf(v);
          }
        }
      }
    }
  }
  #undef PBUF
}

// ---------------- out-proj GEMM (mode-0 scatter), same 3-buffer pipeline ----------------
__global__ __launch_bounds__(256) void k_gemm_out(
    const short* __restrict__ A, const short* __restrict__ BT,
    float* __restrict__ Cf, const int* __restrict__ rowmapC)
{
  #define PBUF (128 * 32)
  __shared__ short As[3 * PBUF];
  __shared__ short Bs[3 * PBUF];
  const int Kdim = 1024;
  int tid = threadIdx.x;
  int lane = tid & 63, wv = tid >> 6;

  int nwg = gridDim.x * gridDim.y;
  int bid = blockIdx.y * gridDim.x + blockIdx.x;
  int cpx = nwg >> 3;
  int swz = (bid & 7) * cpx + (bid >> 3);
  int m0 = (swz / gridDim.x) * 128, n0 = (swz % gridDim.x) * 128;

  int wm = (wv >> 1) * 64, wn = (wv & 1) * 64;
  int fr = lane & 15, quad = lane >> 4;

  int c0 = wv * 128 + lane;
  int c1 = c0 + 64;
  const short* gA0 = A  + (size_t)(m0 + (c0 >> 2)) * Kdim + (c0 & 3) * 8;
  const short* gA1 = A  + (size_t)(m0 + (c1 >> 2)) * Kdim + (c1 & 3) * 8;
  const short* gB0 = BT + (size_t)(n0 + (c0 >> 2)) * Kdim + (c0 & 3) * 8;
  const short* gB1 = BT + (size_t)(n0 + (c1 >> 2)) * Kdim + (c1 & 3) * 8;
  short* lA0 = As + wv * 1024;
  short* lA1 = As + wv * 1024 + 512;
  short* lB0 = Bs + wv * 1024;
  short* lB1 = Bs + wv * 1024 + 512;

  f32x4 acc[4][4];
#pragma unroll
  for (int i = 0; i < 4; i++)
#pragma unroll
    for (int j = 0; j < 4; j++) {
      acc[i][j][0] = 0.f; acc[i][j][1] = 0.f; acc[i][j][2] = 0.f; acc[i][j][3] = 0.f;
    }

  GEMM_PIPE_LOOP()

#pragma unroll
  for (int mt = 0; mt < 4; mt++)
#pragma unroll
    for (int nt = 0; nt < 4; nt++)
#pragma unroll
      for (int r = 0; r < 4; r++) {
        int grow = m0 + wm + mt * 16 + quad * 4 + r;
        int gcol = n0 + wn + nt * 16 + fr;
        int gr = rowmapC[grow];
        Cf[(size_t)gr * 1024 + gcol] = acc[mt][nt][r];
      }
  #undef PBUF
}

// ---------------- merged rotary (q blocks 0..16383, k blocks 16384..49151) ----------------
__global__ __launch_bounds__(256) void k_rot(
    short* __restrict__ qhb, short* __restrict__ khb,
    const float* __restrict__ rotary,
    const int* __restrict__ qtok, const int* __restrict__ kvtok)
{
  int bid = blockIdx.x;
  int lane = threadIdx.x & 63;
  if (bid < 16384) {
    int gw = (bid * 256 + threadIdx.x) >> 6;
    int b = gw >> 14, rem = gw & 16383, h = rem >> 10, q = rem & 1023;
    int tokid = qtok[b * NQc + q];
    float p = rotary[(size_t)tokid * DHH + lane];
    size_t base = ((size_t)(b * HH + h) * NQc + q) * DHH;
    float t = bf2f(qhb[base + lane]);
    float partner = __shfl_xor(t, 32);
    float rh = (lane < 32) ? -partner : partner;
    qhb[base + lane] = f2bf((t * cosf(p) + rh * sinf(p)) * 0.125f);
  } else {
    int gw = ((bid - 16384) * 256 + threadIdx.x) >> 6;
    int b = gw >> 15, rem = gw & 32767, h = rem >> 11, j = rem & 2047;
    int tokid = kvtok[b * NKVc + j];
    float p = rotary[(size_t)tokid * DHH + lane];
    size_t base = ((size_t)(b * HH + h) * NKVc + j) * DHH;
    float t = bf2f(khb[base + lane]);
    float partner = __shfl_xor(t, 32);
    float rh = (lane < 32) ? -partner : partner;
    khb[base + lane] = f2bf(t * cosf(p) + rh * sinf(p));
  }
}

// ---------------- MFMA flash attention (bf16 in, bf16 out) ----------------
#define KP 72    // K/V row pitch (shorts): 144 B -> 2-way frag reads (free)
#define PP2 72   // P row pitch (shorts)
__global__ __launch_bounds__(256) void k_attn_mfma(
    const short* __restrict__ qhb, const short* __restrict__ khb,
    const short* __restrict__ vhbT, const float* __restrict__ nullkv,
    short* __restrict__ attnb)
{
  __shared__ short Kt[2][64][KP];    // [buf][key][d]
  __shared__ short Vt[2][64][KP];    // [buf][d][key]
  __shared__ short Pb[4][16][PP2];   // per-wave P: [q(16)][key(64)]
  int tid = threadIdx.x;
  int lane = tid & 63, wv = tid >> 6;
  int bid = blockIdx.x;
  int xcd = bid & 7, j = bid >> 3;
  int bh = xcd * 8 + (j & 7);
  int qb = j >> 3;
  int q0 = qb * 128 + wv * 32;
  int fr = lane & 15, quad = lane >> 4;
  int b = bh >> 4, h = bh & 15;

  bfrag8 onesf;
#pragma unroll
  for (int e = 0; e < 8; e++) onesf[e] = (short)0x3F80;   // bf16 1.0

  bfrag8 qf[2][2];
#pragma unroll
  for (int qg = 0; qg < 2; qg++) {
    const short* qbase = qhb + ((size_t)bh * NQc + q0 + qg * 16 + fr) * DHH + quad * 8;
    qf[qg][0] = *(const bfrag8*)(qbase);
    qf[qg][1] = *(const bfrag8*)(qbase + 32);
  }

  float sn[2];
#pragma unroll
  for (int qg = 0; qg < 2; qg++) {
    float accn = 0.f;
#pragma unroll
    for (int e = 0; e < 8; e++) {
      accn += bf2f(qf[qg][0][e]) * nullkv[h * DHH + quad * 8 + e];
      accn += bf2f(qf[qg][1][e]) * nullkv[h * DHH + 32 + quad * 8 + e];
    }
    accn += __shfl_xor(accn, 16);
    accn += __shfl_xor(accn, 32);
    sn[qg] = accn;
  }
  float vn[4];
#pragma unroll
  for (int g = 0; g < 4; g++) vn[g] = nullkv[(HH + h) * DHH + g * 16 + fr];

  f32x4 o[2][4], l4[2];
#pragma unroll
  for (int qg = 0; qg < 2; qg++) {
#pragma unroll
    for (int g = 0; g < 4; g++) {
      o[qg][g][0]=0.f; o[qg][g][1]=0.f; o[qg][g][2]=0.f; o[qg][g][3]=0.f;
    }
    l4[qg][0]=0.f; l4[qg][1]=0.f; l4[qg][2]=0.f; l4[qg][3]=0.f;
  }

  int rr = tid >> 3, ch8 = (tid & 7) * 8;
  const short* kp0 = khb + (size_t)bh * NKVc * DHH + (size_t)rr * DHH + ch8;
  const short* kp1 = kp0 + 32 * DHH;
  const short* vp0 = vhbT + ((size_t)bh * DHH + rr) * NKVc + ch8;
  const short* vp1 = vp0 + (size_t)32 * NKVc;

  bfrag8 kr0 = *(const bfrag8*)kp0;
  bfrag8 kr1 = *(const bfrag8*)kp1;
  bfrag8 vr0 = *(const bfrag8*)vp0;
  bfrag8 vr1 = *(const bfrag8*)vp1;

  for (int t = 0; t < 32; t++) {
    int cur = t & 1;
    *(bfrag8*)&Kt[cur][rr][ch8]      = kr0;
    *(bfrag8*)&Kt[cur][rr + 32][ch8] = kr1;
    *(bfrag8*)&Vt[cur][rr][ch8]      = vr0;
    *(bfrag8*)&Vt[cur][rr + 32][ch8] = vr1;
    if (t < 31) {
      size_t ko = (size_t)(t + 1) * 64 * DHH;
      size_t vo = (size_t)(t + 1) * 64;
      kr0 = *(const bfrag8*)(kp0 + ko);
      kr1 = *(const bfrag8*)(kp1 + ko);
      vr0 = *(const bfrag8*)(vp0 + vo);
      vr1 = *(const bfrag8*)(vp1 + vo);
    }
    __builtin_amdgcn_sched_barrier(0);
    asm volatile("s_waitcnt lgkmcnt(0)" ::: "memory");
    __builtin_amdgcn_s_barrier();
    __builtin_amdgcn_sched_barrier(0);

    bfrag8 kf[4][2], vf[4][2];
#pragma unroll
    for (int g = 0; g < 4; g++) {
      kf[g][0] = *(const bfrag8*)&Kt[cur][g * 16 + fr][quad * 8];
      kf[g][1] = *(const bfrag8*)&Kt[cur][g * 16 + fr][32 + quad * 8];
      vf[g][0] = *(const bfrag8*)&Vt[cur][g * 16 + fr][quad * 8];
      vf[g][1] = *(const bfrag8*)&Vt[cur][g * 16 + fr][32 + quad * 8];
    }

#pragma unroll
    for (int qg = 0; qg < 2; qg++) {
      f32x4 sa[4];
#pragma unroll
      for (int g = 0; g < 4; g++) { sa[g][0]=0.f; sa[g][1]=0.f; sa[g][2]=0.f; sa[g][3]=0.f; }
#pragma unroll
      for (int g = 0; g < 4; g++) {
        sa[g] = MFMA_BF16(kf[g][0], qf[qg][0], sa[g]);
        sa[g] = MFMA_BF16(kf[g][1], qf[qg][1], sa[g]);
      }
#pragma unroll
      for (int g = 0; g < 4; g++) {
        short4v p4;
#pragma unroll
        for (int r = 0; r < 4; r++) p4[r] = f2bf_fast(__expf(sa[g][r]));
        *(short4v*)&Pb[wv][fr][g * 16 + quad * 4] = p4;
      }
      bfrag8 pf0 = *(const bfrag8*)&Pb[wv][fr][quad * 8];
      bfrag8 pf1 = *(const bfrag8*)&Pb[wv][fr][32 + quad * 8];
      l4[qg] = MFMA_BF16(pf0, onesf, l4[qg]);
      l4[qg] = MFMA_BF16(pf1, onesf, l4[qg]);
#pragma unroll
      for (int g = 0; g < 4; g++) {
        o[qg][g] = MFMA_BF16(pf0, vf[g][0], o[qg][g]);
        o[qg][g] = MFMA_BF16(pf1, vf[g][1], o[qg][g]);
      }
    }
  }

#pragma unroll
  for (int qg = 0; qg < 2; qg++) {
    float pn[4];
#pragma unroll
    for (int r = 0; r < 4; r++) {
      pn[r] = __expf(__shfl(sn[qg], quad * 4 + r));
      l4[qg][r] += pn[r];
    }
#pragma unroll
    for (int g = 0; g < 4; g++)
#pragma unroll
      for (int r = 0; r < 4; r++)
        o[qg][g][r] += pn[r] * vn[g];
  }
#pragma unroll
  for (int qg = 0; qg < 2; qg++) {
    float inv[4];
#pragma unroll
    for (int r = 0; r < 4; r++) inv[r] = 1.f / l4[qg][r];
#pragma unroll
    for (int r = 0; r < 4; r++) {
      size_t row = (size_t)(b * NQc + q0 + qg * 16 + quad * 4 + r) * DD + h * DHH;
#pragma unroll
      for (int g = 0; g < 4; g++)
        attnb[row + g * 16 + fr] = f2bf(o[qg][g][r] * inv[r]);
    }
  }
}

extern "C" void kernel_launch(void* const* d_in, const int* in_sizes, int n_in,
                              void* d_out, int out_size, void* d_ws, size_t ws_size,
                              hipStream_t stream)
{
  const float* x       = (const float*)d_in[0];
  const float* rotary  = (const float*)d_in[1];
  const float* wrq     = (const float*)d_in[2];
  const float* wrkv    = (const float*)d_in[3];
  const float* wq      = (const float*)d_in[4];
  const float* wkv     = (const float*)d_in[5];
  const float* wout    = (const float*)d_in[6];
  const float* nullkv  = (const float*)d_in[7];
  const float* nulltok = (const float*)d_in[8];
  float* out = (float*)d_out;
  float* ws  = (float*)d_ws;

  // workspace (float offsets), total 21,061,632 floats ~ 84.25 MB (round-3 proven)
  float* logq  = ws;                  // 32768
  float* logkv = ws + 32768;          // 32768
  int*   qtok  = (int*)(ws + 65536);  // 4096
  int*   kvtok = (int*)(ws + 69632);  // 8192
  int*   qmap  = (int*)(ws + 77824);  // 4096 (kvmap contiguous after — k_gather relies on it)
  int*   kvmap = (int*)(ws + 81920);  // 8192 -> 90112
  short* qhb   = (short*)(ws + 90112);     // 4,194,304 sh -> 2,187,264
  short* khb   = (short*)(ws + 2187264);   // 8,388,608 sh -> 6,381,568
  short* vhbT  = (short*)(ws + 6381568);   // 8,388,608 sh -> 10,575,872
  short* attnb = (short*)(ws + 10575872);  // 4,194,304 sh -> 12,673,024
  short* Aq    = (short*)(ws + 12673024);  // 4096*1024 sh (Akv contiguous after)
  short* wqT   = (short*)(ws + 18964480);  // 1024*1024 sh -> 19,488,768
  short* wkvT  = (short*)(ws + 19488768);  // 2048*1024 sh -> 20,537,344
  short* woutT = (short*)(ws + 20537344);  // 1024*1024 sh -> 21,061,632
  short* Akv   = Aq + (size_t)4096 * 1024;

  k_logits<<<2048, 256, 0, stream>>>(x, wrq, wrkv, logq, logkv);
  // route2 (8 blocks) + weight transposes (1024) + out base-fill (512) in ONE launch
  k_route2_plus<<<1544, 1024, 0, stream>>>(
      logq, logkv, 0.1f * logf(1152.f), 0.1f * logf(2304.f),
      qtok, qmap, kvtok, kvmap,
      wq, wkv, wout, wqT, wkvT, woutT, nulltok, out);
  k_gather<<<3072, 256, 0, stream>>>(x, qmap, Aq);   // covers Aq AND Akv
  // q proj + kv proj in ONE launch (256 + 1024 tiles)
  k_gemm_proj<<<1280, 256, 0, stream>>>(Aq, wqT, Akv, wkvT, qhb, khb, vhbT);
  // q rotary + k rotary in ONE launch
  k_rot<<<49152, 256, 0, stream>>>(qhb, khb, rotary, qtok, kvtok);
  k_attn_mfma<<<512, 256, 0, stream>>>(qhb, khb, vhbT, nullkv, attnb);
  // out proj: M=4096 N=1024, scatter rows via qmap (out already base-filled)
  k_gemm_out<<<dim3(8, 32), 256, 0, stream>>>(attnb, woutT, out, qmap);
}